// Round 2
// baseline (964.226 us; speedup 1.0000x reference)
//
#include <hip/hip_runtime.h>

#define BB 2
#define CIN 32
#define COUT 32
#define KK 9
#define PIX 65536          // 256*256 input pixels
#define OH 512
#define OW 512
#define OHOW (OH*OW)
#define NCH 64             // B*COUT
#define TW 16              // tile width (x)
#define TH 8               // tile height (y)
#define TPX (TW*TH)        // 128 px per tile
#define NTX (OW/TW)        // 32
#define NTY (OH/TH)        // 64
#define NTILE (NTX*NTY)    // 2048
#define NBIN (NTILE*KK)    // 18432
#define NPK (PIX*KK)       // 589824 (p,k) pairs
#define ECAP (4*NPK)       // max entries (every splat hits 4 tiles)

// ---- ws layout (bytes) ----
#define OFF_CNT 0                          // u32[NBIN]      (72 KB)
#define OFF_OFF (128*1024)                 // u32[NBIN+1]
#define OFF_CUR (256*1024)                 // u32[NBIN]
#define OFF_WT  (384*1024)                 // f32[KK*32*32]  (36 KB)
#define OFF_XT  (1024*1024)                // f32[PIX*64]    (16 MB)
#define OFF_ENT (OFF_XT + (size_t)PIX*NCH*4)  // u16[ECAP]   (4.7 MB)
#define WS_NEED (OFF_ENT + (size_t)ECAP*2)    // ~21.5 MB

// ============ pass A: x[c][p] -> xT[p][c] (channels-last) ============
__global__ __launch_bounds__(256) void k_transpose_x(
    const float* __restrict__ x, float* __restrict__ xT)
{
    __shared__ float t[64][65];
    const int tid = threadIdx.x, lane = tid & 63, w = tid >> 6;
    const int p0 = blockIdx.x * 64;
    #pragma unroll
    for (int r = 0; r < 16; ++r) {
        const int c = w + 4 * r;
        t[c][lane] = x[(size_t)c * PIX + p0 + lane];     // coalesced
    }
    __syncthreads();
    #pragma unroll
    for (int r = 0; r < 16; ++r) {
        const int pp = w + 4 * r;
        xT[(size_t)(p0 + pp) * NCH + lane] = t[lane][pp]; // coalesced, bank-free
    }
}

// ============ pass A': W[i][o][k] -> WT[k][i][o] ============
__global__ __launch_bounds__(256) void k_transpose_w(
    const float* __restrict__ w, float* __restrict__ wt)
{
    const int t = blockIdx.x * 256 + threadIdx.x;        // k*1024 + i*32 + o
    if (t < CIN * COUT * KK) {
        const int k = t >> 10;
        const int r = t & 1023;
        const int i = r >> 5, o = r & 31;
        wt[t] = w[(i * COUT + o) * KK + k];
    }
}

// corner/tile enumeration shared by count & fill
__device__ __forceinline__ void corners(float sx, float sy,
    int& x0, int& y0, int& x1, int& y1, float& dx, float& dy)
{
    const float x0f = floorf(sx), y0f = floorf(sy);
    dx = sx - x0f; dy = sy - y0f;
    x0 = min(max((int)x0f, 0), OW - 1);
    y0 = min(max((int)y0f, 0), OH - 1);
    x1 = min(x0 + 1, OW - 1);
    y1 = min(y0 + 1, OH - 1);
}

// ============ pass B: count entries per (tile,k) bin ============
__global__ __launch_bounds__(256) void k_count(
    const float* __restrict__ smap, unsigned* __restrict__ cnt)
{
    const int t = blockIdx.x * 256 + threadIdx.x;        // (p,k) flat
    if (t >= NPK) return;
    const int p = t / KK, k = t - p * KK;
    const float sx = smap[2 * t], sy = smap[2 * t + 1];
    int x0, y0, x1, y1; float dx, dy;
    corners(sx, sy, x0, y0, x1, y1, dx, dy);
    const int txa = x0 >> 4, txb = x1 >> 4;
    const int tya = y0 >> 3, tyb = y1 >> 3;
    atomicAdd(&cnt[(tya * NTX + txa) * KK + k], 1u);
    if (txb != txa) atomicAdd(&cnt[(tya * NTX + txb) * KK + k], 1u);
    if (tyb != tya) {
        atomicAdd(&cnt[(tyb * NTX + txa) * KK + k], 1u);
        if (txb != txa) atomicAdd(&cnt[(tyb * NTX + txb) * KK + k], 1u);
    }
}

// ============ pass C: exclusive scan of 18432 counters (1 block) ============
__global__ __launch_bounds__(1024) void k_scan(
    const unsigned* __restrict__ cnt, unsigned* __restrict__ off,
    unsigned* __restrict__ cur)
{
    __shared__ unsigned s[1024];
    const int tid = threadIdx.x;
    unsigned c[18]; unsigned sum = 0;
    const int base = tid * 18;                           // 1024*18 = 18432
    #pragma unroll
    for (int j = 0; j < 18; ++j) { c[j] = cnt[base + j]; sum += c[j]; }
    s[tid] = sum; __syncthreads();
    unsigned val = sum;
    for (int d = 1; d < 1024; d <<= 1) {
        const unsigned v = (tid >= d) ? s[tid - d] : 0u;
        __syncthreads();
        val += v; s[tid] = val;
        __syncthreads();
    }
    unsigned run = val - sum;                            // exclusive prefix
    #pragma unroll
    for (int j = 0; j < 18; ++j) { off[base + j] = run; cur[base + j] = run; run += c[j]; }
    if (tid == 1023) off[NBIN] = run;
}

// ============ pass D: fill entry lists (entry = u16 pixel index) ============
__global__ __launch_bounds__(256) void k_fill(
    const float* __restrict__ smap, unsigned* __restrict__ cur,
    unsigned short* __restrict__ ent)
{
    const int t = blockIdx.x * 256 + threadIdx.x;
    if (t >= NPK) return;
    const int p = t / KK, k = t - p * KK;
    const float sx = smap[2 * t], sy = smap[2 * t + 1];
    int x0, y0, x1, y1; float dx, dy;
    corners(sx, sy, x0, y0, x1, y1, dx, dy);
    const int txa = x0 >> 4, txb = x1 >> 4;
    const int tya = y0 >> 3, tyb = y1 >> 3;
    const unsigned short pv = (unsigned short)p;
    unsigned slot;
    slot = atomicAdd(&cur[(tya * NTX + txa) * KK + k], 1u); ent[slot] = pv;
    if (txb != txa) { slot = atomicAdd(&cur[(tya * NTX + txb) * KK + k], 1u); ent[slot] = pv; }
    if (tyb != tya) {
        slot = atomicAdd(&cur[(tyb * NTX + txa) * KK + k], 1u); ent[slot] = pv;
        if (txb != txa) { slot = atomicAdd(&cur[(tyb * NTX + txb) * KK + k], 1u); ent[slot] = pv; }
    }
}

// ============ pass E: per-tile gather, LDS accumulate, direct store ============
__global__ __launch_bounds__(256, 4) void k_gather(
    const float* __restrict__ xT, const float* __restrict__ wt,
    const float* __restrict__ smap, const unsigned* __restrict__ off,
    const unsigned short* __restrict__ ent, const float* __restrict__ bias,
    float* __restrict__ out)
{
    __shared__ float acc[TPX * 65];                      // [px][65-padded ch] 33.3 KB
    const int tid = threadIdx.x, lane = tid & 63, wid = tid >> 6;
    const int bt = blockIdx.x;                           // tile id
    const int tx0 = (bt & (NTX - 1)) * TW;
    const int ty0 = (bt >> 5) * TH;

    for (int i = tid; i < TPX * 65; i += 256) acc[i] = 0.f;
    __syncthreads();

    const int o = lane & 31, half = lane >> 5;

    for (int k = 0; k < KK; ++k) {
        const int bin = bt * KK + k;
        const unsigned s = off[bin], e_end = off[bin + 1];
        float wreg[CIN];
        #pragma unroll
        for (int i = 0; i < CIN; ++i) wreg[i] = wt[k * 1024 + i * 32 + o];

        for (unsigned e = s + wid; e < e_end; e += 4) {
            int p = (int)ent[e];                         // wave-uniform broadcast
            p = __builtin_amdgcn_readfirstlane(p);
            const float sx = smap[(p * KK + k) * 2];
            const float sy = smap[(p * KK + k) * 2 + 1];
            const float4* xp = (const float4*)(xT + (size_t)p * NCH + half * 32);
            float cv = 0.f;
            #pragma unroll
            for (int j = 0; j < 8; ++j) {
                const float4 xv = xp[j];                 // broadcast 256B of xT[p]
                cv += xv.x * wreg[4*j] + xv.y * wreg[4*j+1]
                    + xv.z * wreg[4*j+2] + xv.w * wreg[4*j+3];
            }
            const float x0f = floorf(sx), y0f = floorf(sy);
            const float dx = sx - x0f, dy = sy - y0f;
            const int x0 = min(max((int)x0f, 0), OW - 1);
            const int y0 = min(max((int)y0f, 0), OH - 1);
            const int x1 = min(x0 + 1, OW - 1), y1 = min(y0 + 1, OH - 1);
            const int lx0 = x0 - tx0, lx1 = x1 - tx0;
            const int ly0 = y0 - ty0, ly1 = y1 - ty0;
            const float wx0 = 1.f - dx, wy0 = 1.f - dy;
            // wave-uniform predicates; each corner owned by exactly one tile
            if ((unsigned)lx0 < TW && (unsigned)ly0 < TH)
                atomicAdd(&acc[(ly0 * TW + lx0) * 65 + lane], cv * wx0 * wy0);
            if ((unsigned)lx1 < TW && (unsigned)ly0 < TH)
                atomicAdd(&acc[(ly0 * TW + lx1) * 65 + lane], cv * dx * wy0);
            if ((unsigned)lx0 < TW && (unsigned)ly1 < TH)
                atomicAdd(&acc[(ly1 * TW + lx0) * 65 + lane], cv * wx0 * dy);
            if ((unsigned)lx1 < TW && (unsigned)ly1 < TH)
                atomicAdd(&acc[(ly1 * TW + lx1) * 65 + lane], cv * dx * dy);
        }
    }
    __syncthreads();

    // flush: out[c][q] = acc[px][c] + bias, plain coalesced stores
    #pragma unroll
    for (int h = 0; h < 2; ++h) {
        const int px = h * 64 + lane;
        const int py = px >> 4, pxx = px & 15;
        const size_t q = (size_t)(ty0 + py) * OW + tx0 + pxx;
        #pragma unroll
        for (int j = 0; j < 16; ++j) {
            const int c = wid * 16 + j;
            out[(size_t)c * OHOW + q] = acc[px * 65 + c] + bias[c & 31];
        }
    }
}

// ============ fallback (round-1 path, used only if ws too small) ============
__global__ __launch_bounds__(576) void mtc_scatter_direct(
    const float* __restrict__ x, const float* __restrict__ weight,
    const float* __restrict__ smap, float* __restrict__ acc)
{
    __shared__ float xs[64][68];
    __shared__ float sm[64 * KK * 2];
    const int t = threadIdx.x;
    const int p0 = blockIdx.x * 64;
    if (t < 512) {
        const int pp = t & 63, c0 = t >> 6;
        #pragma unroll
        for (int ch = 0; ch < 8; ++ch) {
            const int c = c0 + ch * 8;
            xs[pp][c] = x[(size_t)c * PIX + p0 + pp];
        }
    }
    for (int i = t; i < 64 * KK * 2; i += 576)
        sm[i] = smap[(size_t)p0 * (KK * 2) + i];
    const int k = t >> 6, lane = t & 63, b = lane >> 5, o = lane & 31;
    float wreg[CIN];
    #pragma unroll
    for (int i = 0; i < CIN; ++i) wreg[i] = weight[(i * COUT + o) * KK + k];
    __syncthreads();
    for (int pp = 0; pp < 64; ++pp) {
        const float sx = sm[(pp * KK + k) * 2], sy = sm[(pp * KK + k) * 2 + 1];
        int x0, y0, x1, y1; float dx, dy;
        corners(sx, sy, x0, y0, x1, y1, dx, dy);
        const float* xrow = &xs[pp][b * 32];
        float cv = 0.f;
        #pragma unroll
        for (int j = 0; j < 8; ++j) {
            const float4 xv = *(const float4*)(xrow + 4 * j);
            cv += xv.x * wreg[4*j] + xv.y * wreg[4*j+1] + xv.z * wreg[4*j+2] + xv.w * wreg[4*j+3];
        }
        const size_t base = (size_t)lane * OHOW;
        atomicAdd(&acc[base + y0 * OW + x0], cv * (1.f - dx) * (1.f - dy));
        atomicAdd(&acc[base + y0 * OW + x1], cv * dx * (1.f - dy));
        atomicAdd(&acc[base + y1 * OW + x0], cv * (1.f - dx) * dy);
        atomicAdd(&acc[base + y1 * OW + x1], cv * dx * dy);
    }
}

__global__ __launch_bounds__(256) void mtc_bias_add(
    float* __restrict__ out, const float* __restrict__ bias)
{
    const size_t i = (size_t)blockIdx.x * 256 + threadIdx.x;
    out[i] += bias[(i >> 18) & 31];
}

extern "C" void kernel_launch(void* const* d_in, const int* in_sizes, int n_in,
                              void* d_out, int out_size, void* d_ws, size_t ws_size,
                              hipStream_t stream) {
    const float* x      = (const float*)d_in[0];
    const float* weight = (const float*)d_in[1];
    const float* bias   = (const float*)d_in[2];
    const float* smap   = (const float*)d_in[3];
    float* out = (float*)d_out;
    char* ws = (char*)d_ws;

    if (ws_size >= WS_NEED) {
        unsigned* cnt = (unsigned*)(ws + OFF_CNT);
        unsigned* off = (unsigned*)(ws + OFF_OFF);
        unsigned* cur = (unsigned*)(ws + OFF_CUR);
        float* wt     = (float*)(ws + OFF_WT);
        float* xT     = (float*)(ws + OFF_XT);
        unsigned short* ent = (unsigned short*)(ws + OFF_ENT);

        hipMemsetAsync(cnt, 0, NBIN * sizeof(unsigned), stream);
        k_transpose_x<<<PIX / 64, 256, 0, stream>>>(x, xT);
        k_transpose_w<<<(CIN * COUT * KK + 255) / 256, 256, 0, stream>>>(weight, wt);
        k_count<<<NPK / 256, 256, 0, stream>>>(smap, cnt);
        k_scan<<<1, 1024, 0, stream>>>(cnt, off, cur);
        k_fill<<<NPK / 256, 256, 0, stream>>>(smap, cur, ent);
        k_gather<<<NTILE, 256, 0, stream>>>(xT, wt, smap, off, ent, bias, out);
    } else {
        hipMemsetAsync(out, 0, (size_t)OHOW * NCH * sizeof(float), stream);
        mtc_scatter_direct<<<PIX / 64, 576, 0, stream>>>(x, weight, smap, out);
        mtc_bias_add<<<(OHOW * NCH) / 256, 256, 0, stream>>>(out, bias);
    }
}